// Round 11
// baseline (78.700 us; speedup 1.0000x reference)
//
#include <hip/hip_runtime.h>
#include <hip/hip_bf16.h>
#include <math.h>

// SimpleMemoryBank: B=8,T=4096,D=512,SLOTS=128,TOPK=8
#define R_TOTAL 32768
#define DM      512
#define NSLOT   128
#define KSEL    8

typedef _Float16 half8 __attribute__((ext_vector_type(8)));
typedef float    floatx4 __attribute__((ext_vector_type(4)));

// ---------------- prep: split K into f16 hi/lo AND pre-swizzle into chunk-major staged
// layout Ks[c][u][slot][8] (u=0..3 hi-planes kg, u=4..7 lo-planes kg). Each chunk's
// 16 KB contiguous -> main kernel's global_load_lds is lane-coalesced (R8 win).
__global__ void smb_prepK(const float* __restrict__ Km, _Float16* __restrict__ Ks) {
  const int i = blockIdx.x * 256 + threadIdx.x;   // 65536 = slot*512 + d
  const int slot = i >> 9;
  const int d    = i & 511;
  const float f  = Km[i] * 256.0f;                // exact (power of 2)
  const _Float16 h  = (_Float16)f;
  const _Float16 lo = (_Float16)(f - (float)h);   // exact residual (Sterbenz)
  const int c  = d >> 5;          // chunk 0..15
  const int kg = (d >> 3) & 3;    // plane-within-chunk 0..3
  const int j  = d & 7;
  Ks[((((c * 8) + kg    ) * NSLOT + slot) << 3) + j] = h;    // hi plane u=kg
  Ks[((((c * 8) + 4 + kg) * NSLOT + slot) << 3) + j] = lo;   // lo plane u=4+kg
}

// async 16B global->LDS (width literal 16; LDS dest = wave-uniform base + lane*16)
__device__ __forceinline__ void load16_lds(const _Float16* g, _Float16* l) {
  __builtin_amdgcn_global_load_lds(
      (const __attribute__((address_space(1))) unsigned int*)g,
      (__attribute__((address_space(3))) unsigned int*)l, 16, 0, 0);
}

// ---------------- fused main ---------------------------------------------------------------
// 512-thread blocks, 8 waves = 2 row-groups x 4 slot-quarters; 32 rows/block, grid 1024.
// R10 lesson: occupancy was GRID-capped (512 blocks = 2 blocks/CU) and launch_bounds(512,8)
// VGPR-capped to 32 -> spills. Now: grid 1024, union LDS 32KB -> 4 blocks/CU = 32 waves/CU
// provided VGPR<=64 (launch_bounds(512,4); acc halved to 2 frags -> ~48 expected).
// q fragments read by 4 lockstep waves/block: 4KB/chunk window -> L1-resident.
__global__ __launch_bounds__(512, 4) void smb_main(
    const float* __restrict__ q,     // [R_TOTAL, DM]
    const _Float16* __restrict__ Ks, // [16][8][NSLOT][8] staged chunk-major split-K
    const float* __restrict__ Vm,    // [NSLOT, DM]
    const float* __restrict__ sal,   // [NSLOT]
    float* __restrict__ outv,        // [R_TOTAL, DM]
    float* __restrict__ outw)        // [R_TOTAL, KSEL]
{
  __shared__ union U {
    _Float16 stage[2][8][NSLOT][8];  // 32768 B, live: prologue .. last-chunk MFMA reads
    float    slab[32][132];          // 16896 B, live: epilogue .. Phase B
  } u;

  const int t  = threadIdx.x;
  const int w  = t >> 6;          // wave 0..7
  const int l  = t & 63;          // lane
  const int li = l & 15;          // M-row / B-col within fragment
  const int kg = l >> 4;          // k-group 0..3
  const int rg = w >> 2;          // row group 0..1
  const int sq = w & 3;           // slot quarter 0..3
  const int r0b = blockIdx.x * 32;
  const int r0w = r0b + rg * 16;  // this wave's 16 q rows

  const float* qrow = q + (size_t)(r0w + li) * DM + kg * 8;

  floatx4 acc[2];
#pragma unroll
  for (int g = 0; g < 2; ++g) acc[g] = (floatx4){0.f, 0.f, 0.f, 0.f};

  // ---- prologue: stage chunk 0 (wave w -> plane u=w); q prefetch distance 2 ----
#pragma unroll
  for (int p = 0; p < 2; ++p) {
    const _Float16* src = Ks + ((((size_t)0 * 8 + w) * NSLOT + p * 64 + l) << 3);
    load16_lds(src, &u.stage[0][w][p * 64 + l][0]);
  }
  float4 q0c = *(const float4*)(qrow + 0);
  float4 q1c = *(const float4*)(qrow + 4);
  float4 q0n = *(const float4*)(qrow + 32);
  float4 q1n = *(const float4*)(qrow + 36);
  __syncthreads();   // vmcnt(0) drained before s_barrier -> stage(0) resident

  // ---- main loop: stage(c+1) + q(c+2) issued BEFORE compute(c); one barrier per chunk ----
#pragma unroll 2
  for (int c = 0; c < 16; ++c) {
    const int cb = c & 1, nb = cb ^ 1;
    float4 q0nn, q1nn;
    if (c < 15) {
#pragma unroll
      for (int p = 0; p < 2; ++p) {
        const _Float16* src = Ks + ((((size_t)(c + 1) * 8 + w) * NSLOT + p * 64 + l) << 3);
        load16_lds(src, &u.stage[nb][w][p * 64 + l][0]);
      }
    }
    if (c < 14) {
      q0nn = *(const float4*)(qrow + (c + 2) * 32);
      q1nn = *(const float4*)(qrow + (c + 2) * 32 + 4);
    }

    // compute chunk c: fragments from LDS, f16-split MFMA (3 terms, ~1e-8 rel exact)
    half8 a1, a2;
#pragma unroll
    for (int j = 0; j < 4; ++j) {
      const float f0 = q0c[j] * 16.0f;   // exact scale
      const float f1 = q1c[j] * 16.0f;
      const _Float16 h0 = (_Float16)f0;
      const _Float16 h1 = (_Float16)f1;
      a1[j]     = h0;  a2[j]     = (_Float16)(f0 - (float)h0);
      a1[4 + j] = h1;  a2[4 + j] = (_Float16)(f1 - (float)h1);
    }
#pragma unroll
    for (int g = 0; g < 2; ++g) {
      const int slot = sq * 32 + g * 16 + li;
      const half8 b1 = *(const half8*)&u.stage[cb][kg][slot][0];
      const half8 b2 = *(const half8*)&u.stage[cb][4 + kg][slot][0];
      acc[g] = __builtin_amdgcn_mfma_f32_16x16x32_f16(a1, b1, acc[g], 0, 0, 0);
      acc[g] = __builtin_amdgcn_mfma_f32_16x16x32_f16(a2, b1, acc[g], 0, 0, 0);
      acc[g] = __builtin_amdgcn_mfma_f32_16x16x32_f16(a1, b2, acc[g], 0, 0, 0);
    }
    q0c = q0n; q1c = q1n;
    if (c < 14) { q0n = q0nn; q1n = q1nn; }
    __syncthreads();   // all waves done reading stage[cb]; after c==15 this also
                       // guarantees stage is dead -> slab (union alias) may be written
  }

  // ---- epilogue: scores = (acc/4096)/sqrt(D) + salience -> block slab ----
  // D-frag layout (m89-verified): col = lane&15 (slot), row = (lane>>4)*4 + reg (q row)
  const float den = sqrtf((float)DM);
#pragma unroll
  for (int g = 0; g < 2; ++g) {
    const int col = sq * 32 + g * 16 + li;
    const float sv = sal[col];
#pragma unroll
    for (int i = 0; i < 4; ++i) {
      const float s = (acc[g][i] * 0.000244140625f) / den + sv;  // *2^-12 exact, IEEE div
      u.slab[rg * 16 + kg * 4 + i][col] = s;
    }
  }
  __syncthreads();   // slab written by all 4 slot-quarter waves

  // ---- Phase B: per-row top-8 (tie: lower index) + softmax. 16 lanes/row. ----
  const int row = t >> 4;   // 0..31
  const int lq  = t & 15;

  float bs[8]; int bi[8];
#pragma unroll
  for (int p = 0; p < 8; ++p) { bs[p] = -3.0e38f; bi[p] = 0x7fffffff; }

#pragma unroll
  for (int jj = 0; jj < 8; ++jj) {
    const int   j = jj * 16 + lq;
    const float s = u.slab[row][j];
    bool c[8];
#pragma unroll
    for (int p = 0; p < 8; ++p) c[p] = s > bs[p];   // strict > keeps earlier index on ties
    float nb[8]; int ni[8];
    nb[0] = c[0] ? s : bs[0];
    ni[0] = c[0] ? j : bi[0];
#pragma unroll
    for (int p = 7; p >= 1; --p) {
      nb[p] = c[p] ? (c[p - 1] ? bs[p - 1] : s) : bs[p];
      ni[p] = c[p] ? (c[p - 1] ? bi[p - 1] : j) : bi[p];
    }
#pragma unroll
    for (int p = 0; p < 8; ++p) { bs[p] = nb[p]; bi[p] = ni[p]; }
  }

  // merge 16 sorted lists via 4-stage butterflies (score desc, index asc) + pop
  float ts[8]; int ti_[8];
#pragma unroll
  for (int r = 0; r < 8; ++r) {
    float hs = bs[0]; int hi = bi[0];
#pragma unroll
    for (int m = 1; m <= 8; m <<= 1) {
      const float os = __shfl_xor(hs, m, 64);
      const int   oi = __shfl_xor(hi, m, 64);
      if (os > hs || (os == hs && oi < hi)) { hs = os; hi = oi; }
    }
    ts[r] = hs; ti_[r] = hi;
    if (bs[0] == hs && bi[0] == hi) {   // winner lane pops its head (static shift)
#pragma unroll
      for (int p = 0; p < 7; ++p) { bs[p] = bs[p + 1]; bi[p] = bi[p + 1]; }
      bs[7] = -3.0e38f; bi[7] = 0x7fffffff;
    }
  }

  // softmax over the 8 selected scores; all 16 lanes hold the result redundantly
  float tw[8];
  const float mx = ts[0];
  float esum = 0.0f;
#pragma unroll
  for (int r = 0; r < 8; ++r) { tw[r] = expf(ts[r] - mx); esum += tw[r]; }
#pragma unroll
  for (int r = 0; r < 8; ++r) tw[r] /= esum;

  if (lq == 0) {
#pragma unroll
    for (int r = 0; r < 8; ++r) outw[(size_t)(r0b + row) * KSEL + r] = tw[r];
  }

  // ---- Phase C: read_vectors = sum_k w_k * V[idx_k]; top-k state already in registers ----
  const float4* __restrict__ V4 = (const float4*)Vm;
  float4* __restrict__ O4 = (float4*)outv;
  const size_t obase = (size_t)(r0b + row) * (DM / 4);
#pragma unroll 4
  for (int cc = 0; cc < 8; ++cc) {
    const int cdx = cc * 16 + lq;   // 16 lanes cover 256B contiguous per step
    float4 a; a.x = a.y = a.z = a.w = 0.0f;
#pragma unroll
    for (int r = 0; r < 8; ++r) {   // k ascending, matches reference einsum order
      const float4 v = V4[(size_t)ti_[r] * (DM / 4) + cdx];
      a.x = fmaf(tw[r], v.x, a.x);
      a.y = fmaf(tw[r], v.y, a.y);
      a.z = fmaf(tw[r], v.z, a.z);
      a.w = fmaf(tw[r], v.w, a.w);
    }
    O4[obase + cdx] = a;
  }
}

extern "C" void kernel_launch(void* const* d_in, const int* in_sizes, int n_in,
                              void* d_out, int out_size, void* d_ws, size_t ws_size,
                              hipStream_t stream) {
  const float* q   = (const float*)d_in[0];
  const float* Km  = (const float*)d_in[1];
  const float* Vm  = (const float*)d_in[2];
  const float* sal = (const float*)d_in[3];
  // d_in[4] = topk (fixed 8)

  float* outv = (float*)d_out;
  float* outw = outv + (size_t)R_TOTAL * DM;

  _Float16* Ks = (_Float16*)d_ws;   // 256 KB staged chunk-major split-K

  hipLaunchKernelGGL(smb_prepK, dim3((NSLOT * DM) / 256), dim3(256), 0, stream, Km, Ks);
  hipLaunchKernelGGL(smb_main, dim3(R_TOTAL / 32), dim3(512), 0, stream,
                     q, Ks, Vm, sal, outv, outw);
}

// Round 12
// 68.107 us; speedup vs baseline: 1.1555x; 1.1555x over previous
//
#include <hip/hip_runtime.h>
#include <hip/hip_bf16.h>
#include <math.h>

// SimpleMemoryBank: B=8,T=4096,D=512,SLOTS=128,TOPK=8
#define R_TOTAL 32768
#define DM      512
#define NSLOT   128
#define KSEL    8

typedef _Float16 half8 __attribute__((ext_vector_type(8)));
typedef float    floatx4 __attribute__((ext_vector_type(4)));

// ---------------- prep: split K into f16 hi/lo, pre-swizzled chunk-major staged layout
// Ks[oc][u][slot][8] for oc=0..15 (k=[oc*32,oc*32+32)), u=0..3 hi-planes kg, 4..7 lo.
// Identical to R8 (proven). Main kernel consumes two oc per BK=64 iteration.
__global__ void smb_prepK(const float* __restrict__ Km, _Float16* __restrict__ Ks) {
  const int i = blockIdx.x * 256 + threadIdx.x;   // 65536 = slot*512 + d
  const int slot = i >> 9;
  const int d    = i & 511;
  const float f  = Km[i] * 256.0f;                // exact (power of 2)
  const _Float16 h  = (_Float16)f;
  const _Float16 lo = (_Float16)(f - (float)h);   // exact residual (Sterbenz)
  const int c  = d >> 5;          // oc 0..15
  const int kg = (d >> 3) & 3;    // plane-within-chunk 0..3
  const int j  = d & 7;
  Ks[((((c * 8) + kg    ) * NSLOT + slot) << 3) + j] = h;    // hi plane u=kg
  Ks[((((c * 8) + 4 + kg) * NSLOT + slot) << 3) + j] = lo;   // lo plane u=4+kg
}

// async 16B global->LDS (width literal 16; LDS dest = wave-uniform base + lane*16)
__device__ __forceinline__ void load16_lds(const _Float16* g, _Float16* l) {
  __builtin_amdgcn_global_load_lds(
      (const __attribute__((address_space(1))) unsigned int*)g,
      (__attribute__((address_space(3))) unsigned int*)l, 16, 0, 0);
}

// ---------------- fused main ---------------------------------------------------------------
// R8 shape (proven 56.8us): 512 threads, 8 waves = 4 row-groups x 2 slot-halves,
// 64 rows/block, grid 512. Changes vs R8 (work removal, not occupancy):
//  - BK=64: 8 K-iterations -> barrier count 18->10 (each barrier = full vmcnt drain stall)
//  - stage/slab LDS union (disjoint lifetimes): 64KB total, still 2 blocks/CU
//  - Phase B slab reads vectorized: 4x ds_read_b128 per lane instead of 16 scalar
__global__ __launch_bounds__(512, 4) void smb_main(
    const float* __restrict__ q,     // [R_TOTAL, DM]
    const _Float16* __restrict__ Ks, // [16][8][NSLOT][8] staged chunk-major split-K
    const float* __restrict__ Vm,    // [NSLOT, DM]
    const float* __restrict__ sal,   // [NSLOT]
    float* __restrict__ outv,        // [R_TOTAL, DM]
    float* __restrict__ outw)        // [R_TOTAL, KSEL]
{
  __shared__ union U {
    _Float16 stage[2][2][8][NSLOT][8]; // 65536 B: [buf][sub(oc parity)][u][slot][8]
    float    slab[64][132];            // 33792 B, live only after GEMM
  } u;

  const int t  = threadIdx.x;
  const int w  = t >> 6;          // wave 0..7
  const int l  = t & 63;          // lane
  const int li = l & 15;          // M-row / B-col within fragment
  const int kg = l >> 4;          // k-group 0..3
  const int rg = w >> 1;          // row group 0..3
  const int sh = w & 1;           // slot half 0..1
  const int r0b = blockIdx.x * 64;
  const int r0w = r0b + rg * 16;  // this wave's 16 q rows

  const float* qrow = q + (size_t)(r0w + li) * DM + kg * 8;

  floatx4 acc[4];
#pragma unroll
  for (int g = 0; g < 4; ++g) acc[g] = (floatx4){0.f, 0.f, 0.f, 0.f};

  // ---- prologue: stage BK-chunk 0 (oc 0,1); load q chunk 0 ----
  // staging per iter: 32KB = 8 waves x 4 instrs; instr i: sub=i>>1, p=i&1, plane u=w
#pragma unroll
  for (int i = 0; i < 4; ++i) {
    const int sub = i >> 1, p = i & 1;
    const _Float16* src = Ks + ((((size_t)(0 + sub) * 8 + w) * NSLOT + p * 64 + l) << 3);
    load16_lds(src, &u.stage[0][sub][w][p * 64 + l][0]);
  }
  float4 qc0 = *(const float4*)(qrow + 0);
  float4 qc1 = *(const float4*)(qrow + 4);
  float4 qc2 = *(const float4*)(qrow + 32);
  float4 qc3 = *(const float4*)(qrow + 36);
  __syncthreads();   // vmcnt(0) drained before s_barrier -> stage(0) resident

  // ---- main loop: 8 BK=64 iterations; stage(c+1)+q(c+1) issued BEFORE compute(c) ----
#pragma unroll 2
  for (int c = 0; c < 8; ++c) {
    const int cb = c & 1, nb = cb ^ 1;
    float4 qn0, qn1, qn2, qn3;
    if (c < 7) {
#pragma unroll
      for (int i = 0; i < 4; ++i) {
        const int sub = i >> 1, p = i & 1;
        const _Float16* src =
            Ks + ((((size_t)(2 * (c + 1) + sub) * 8 + w) * NSLOT + p * 64 + l) << 3);
        load16_lds(src, &u.stage[nb][sub][w][p * 64 + l][0]);
      }
      qn0 = *(const float4*)(qrow + (c + 1) * 64);
      qn1 = *(const float4*)(qrow + (c + 1) * 64 + 4);
      qn2 = *(const float4*)(qrow + (c + 1) * 64 + 32);
      qn3 = *(const float4*)(qrow + (c + 1) * 64 + 36);
    }

    // compute: two k=32 sub-chunks, f16-split MFMA (3 terms, ~1e-8 rel exact)
#pragma unroll
    for (int sub = 0; sub < 2; ++sub) {
      const float4 qa = sub ? qc2 : qc0;
      const float4 qb = sub ? qc3 : qc1;
      half8 a1, a2;
#pragma unroll
      for (int j = 0; j < 4; ++j) {
        const float f0 = qa[j] * 16.0f;   // exact scale
        const float f1 = qb[j] * 16.0f;
        const _Float16 h0 = (_Float16)f0;
        const _Float16 h1 = (_Float16)f1;
        a1[j]     = h0;  a2[j]     = (_Float16)(f0 - (float)h0);
        a1[4 + j] = h1;  a2[4 + j] = (_Float16)(f1 - (float)h1);
      }
#pragma unroll
      for (int g = 0; g < 4; ++g) {
        const int slot = sh * 64 + g * 16 + li;
        const half8 b1 = *(const half8*)&u.stage[cb][sub][kg][slot][0];
        const half8 b2 = *(const half8*)&u.stage[cb][sub][4 + kg][slot][0];
        acc[g] = __builtin_amdgcn_mfma_f32_16x16x32_f16(a1, b1, acc[g], 0, 0, 0);
        acc[g] = __builtin_amdgcn_mfma_f32_16x16x32_f16(a2, b1, acc[g], 0, 0, 0);
        acc[g] = __builtin_amdgcn_mfma_f32_16x16x32_f16(a1, b2, acc[g], 0, 0, 0);
      }
    }
    qc0 = qn0; qc1 = qn1; qc2 = qn2; qc3 = qn3;
    __syncthreads();   // all waves done reading stage[cb]; after c==7 also makes
                       // stage dead -> slab (union alias) may be written
  }

  // ---- epilogue: scores = (acc/4096)/sqrt(D) + salience -> block slab ----
  // D-frag layout (m89-verified): col = lane&15 (slot), row = (lane>>4)*4 + reg (q row)
  const float den = sqrtf((float)DM);
#pragma unroll
  for (int g = 0; g < 4; ++g) {
    const int col = sh * 64 + g * 16 + li;
    const float sv = sal[col];
#pragma unroll
    for (int i = 0; i < 4; ++i) {
      const float s = (acc[g][i] * 0.000244140625f) / den + sv;  // *2^-12 exact, IEEE div
      u.slab[rg * 16 + kg * 4 + i][col] = s;
    }
  }
  __syncthreads();   // slab written by both slot-half waves

  // ---- Phase B: per-row top-8 (tie: lower index) + softmax. 8 lanes/row. ----
  // Lane lq owns contiguous j-block [lq*16, lq*16+16): 4 x b128 reads, scan ascending j.
  const int row = t >> 3;   // 0..63
  const int lq  = t & 7;

  float bs[8]; int bi[8];
#pragma unroll
  for (int p = 0; p < 8; ++p) { bs[p] = -3.0e38f; bi[p] = 0x7fffffff; }

#pragma unroll
  for (int e4 = 0; e4 < 4; ++e4) {
    const float4 v = *(const float4*)&u.slab[row][lq * 16 + e4 * 4];
#pragma unroll
    for (int ei = 0; ei < 4; ++ei) {
      const int   j = lq * 16 + e4 * 4 + ei;
      const float s = (ei == 0) ? v.x : (ei == 1) ? v.y : (ei == 2) ? v.z : v.w;
      bool c[8];
#pragma unroll
      for (int p = 0; p < 8; ++p) c[p] = s > bs[p];  // strict > keeps earlier index on ties
      float nb_[8]; int ni[8];
      nb_[0] = c[0] ? s : bs[0];
      ni[0]  = c[0] ? j : bi[0];
#pragma unroll
      for (int p = 7; p >= 1; --p) {
        nb_[p] = c[p] ? (c[p - 1] ? bs[p - 1] : s) : bs[p];
        ni[p]  = c[p] ? (c[p - 1] ? bi[p - 1] : j) : bi[p];
      }
#pragma unroll
      for (int p = 0; p < 8; ++p) { bs[p] = nb_[p]; bi[p] = ni[p]; }
    }
  }

  // merge 8 sorted lists via oct butterflies (score desc, index asc) + pop
  float ts[8]; int ti_[8];
#pragma unroll
  for (int r = 0; r < 8; ++r) {
    float hs = bs[0]; int hi = bi[0];
#pragma unroll
    for (int m = 1; m <= 4; m <<= 1) {
      const float os = __shfl_xor(hs, m, 64);
      const int   oi = __shfl_xor(hi, m, 64);
      if (os > hs || (os == hs && oi < hi)) { hs = os; hi = oi; }
    }
    ts[r] = hs; ti_[r] = hi;
    if (bs[0] == hs && bi[0] == hi) {   // winner lane pops its head (static shift)
#pragma unroll
      for (int p = 0; p < 7; ++p) { bs[p] = bs[p + 1]; bi[p] = bi[p + 1]; }
      bs[7] = -3.0e38f; bi[7] = 0x7fffffff;
    }
  }

  // softmax over the 8 selected scores; all 8 lanes hold the result redundantly
  float tw[8];
  const float mx = ts[0];
  float esum = 0.0f;
#pragma unroll
  for (int r = 0; r < 8; ++r) { tw[r] = expf(ts[r] - mx); esum += tw[r]; }
#pragma unroll
  for (int r = 0; r < 8; ++r) tw[r] /= esum;

  if (lq == 0) {
#pragma unroll
    for (int r = 0; r < 8; ++r) outw[(size_t)(r0b + row) * KSEL + r] = tw[r];
  }

  // ---- Phase C: read_vectors = sum_k w_k * V[idx_k]; top-k state already in registers ----
  const float4* __restrict__ V4 = (const float4*)Vm;
  float4* __restrict__ O4 = (float4*)outv;
  const size_t obase = (size_t)(r0b + row) * (DM / 4);
#pragma unroll 4
  for (int cc = 0; cc < 16; ++cc) {
    const int cdx = cc * 8 + lq;    // 8 lanes cover 128B contiguous per step
    float4 a; a.x = a.y = a.z = a.w = 0.0f;
#pragma unroll
    for (int r = 0; r < 8; ++r) {   // k ascending, matches reference einsum order
      const float4 v = V4[(size_t)ti_[r] * (DM / 4) + cdx];
      a.x = fmaf(tw[r], v.x, a.x);
      a.y = fmaf(tw[r], v.y, a.y);
      a.z = fmaf(tw[r], v.z, a.z);
      a.w = fmaf(tw[r], v.w, a.w);
    }
    O4[obase + cdx] = a;
  }
}

extern "C" void kernel_launch(void* const* d_in, const int* in_sizes, int n_in,
                              void* d_out, int out_size, void* d_ws, size_t ws_size,
                              hipStream_t stream) {
  const float* q   = (const float*)d_in[0];
  const float* Km  = (const float*)d_in[1];
  const float* Vm  = (const float*)d_in[2];
  const float* sal = (const float*)d_in[3];
  // d_in[4] = topk (fixed 8)

  float* outv = (float*)d_out;
  float* outw = outv + (size_t)R_TOTAL * DM;

  _Float16* Ks = (_Float16*)d_ws;   // 256 KB staged chunk-major split-K

  hipLaunchKernelGGL(smb_prepK, dim3((NSLOT * DM) / 256), dim3(256), 0, stream, Km, Ks);
  hipLaunchKernelGGL(smb_main, dim3(R_TOTAL / 64), dim3(512), 0, stream,
                     q, Ks, Vm, sal, outv, outw);
}

// Round 13
// 57.198 us; speedup vs baseline: 1.3759x; 1.1907x over previous
//
#include <hip/hip_runtime.h>
#include <hip/hip_bf16.h>
#include <math.h>

// SimpleMemoryBank: B=8,T=4096,D=512,SLOTS=128,TOPK=8
#define R_TOTAL 32768
#define DM      512
#define NSLOT   128
#define KSEL    8

typedef _Float16 half8 __attribute__((ext_vector_type(8)));
typedef float    floatx4 __attribute__((ext_vector_type(4)));

// ---------------- prep: (1) split K into f16 hi/lo in chunk-major staged layout (R8-proven);
// (2) V^T in f16, XOR-swizzled so GEMM2's linear global_load_lds + swizzled ds_read_b128
// is bank-balanced (T2/m173: swizzle source + read, keep LDS linear).
__global__ void smb_prep(const float* __restrict__ Km, const float* __restrict__ Vm,
                         _Float16* __restrict__ Ks, _Float16* __restrict__ Vt) {
  const int i = blockIdx.x * 256 + threadIdx.x;   // 0..65535
  // K part: i = slot*512 + d
  {
    const int slot = i >> 9;
    const int d    = i & 511;
    const float f  = Km[i] * 256.0f;              // exact (power of 2)
    const _Float16 h  = (_Float16)f;
    const _Float16 lo = (_Float16)(f - (float)h); // exact residual (Sterbenz)
    const int c  = d >> 5;
    const int kg = (d >> 3) & 3;
    const int j  = d & 7;
    Ks[((((c * 8) + kg    ) * NSLOT + slot) << 3) + j] = h;
    Ks[((((c * 8) + 4 + kg) * NSLOT + slot) << 3) + j] = lo;
  }
  // Vt part: i = d*128 + slot (write-coalesced); logical Vt[d][slot] = V[slot][d],
  // stored swizzled: slot' = slot ^ ((d&7)<<3), chunked by 64 d-rows.
  {
    const int d    = i >> 7;
    const int slot = i & 127;
    const float v  = Vm[(size_t)slot * DM + d];
    const int idx  = (d >> 6) * 8192 + (d & 63) * 128 + (slot ^ ((d & 7) << 3));
    Vt[idx] = (_Float16)v;
  }
}

// async 16B global->LDS (width literal 16; LDS dest = wave-uniform base + lane*16)
__device__ __forceinline__ void load16_lds(const _Float16* g, _Float16* l) {
  __builtin_amdgcn_global_load_lds(
      (const __attribute__((address_space(1))) unsigned int*)g,
      (__attribute__((address_space(3))) unsigned int*)l, 16, 0, 0);
}

// ---------------- fused main ---------------------------------------------------------------
// GEMM1/topk/softmax/outw: byte-identical to R8 (proven 56.8us local optimum).
// Phase C replaced by GEMM2: outv = W_dense @ V^T via MFMA (W = scattered softmax weights,
// f16 hi+lo; V single f16). Removes 512MB L2 gather + ~670 VALU/wave.
__global__ __launch_bounds__(512, 4) void smb_main(
    const float* __restrict__ q,     // [R_TOTAL, DM]
    const _Float16* __restrict__ Ks, // [16][8][NSLOT][8] staged chunk-major split-K
    const _Float16* __restrict__ Vt, // [8 chunks][64 d][128 slots swz] f16
    const float* __restrict__ sal,   // [NSLOT]
    float* __restrict__ outv,        // [R_TOTAL, DM]
    float* __restrict__ outw)        // [R_TOTAL, KSEL]
{
  __shared__ union R1 {              // GEMM1 K-stage  |  GEMM2 W-dense (disjoint lifetimes)
    _Float16 stage[2][8][NSLOT][8];  // 32768 B
    _Float16 W[2][64][136];          // 34816 B ([0]=hi,[1]=lo; stride 136 -> 272B, 16B-align)
  } r1;
  __shared__ union R2 {              // score slab     |  GEMM2 V^T chunks (disjoint)
    float    slab[64][132];          // 33792 B
    _Float16 vt[2][8192];            // 32768 B (2 x 16KB double buffer)
  } r2;

  const int t  = threadIdx.x;
  const int w  = t >> 6;          // wave 0..7
  const int l  = t & 63;          // lane
  const int li = l & 15;          // M-row / B-col within fragment
  const int kg = l >> 4;          // k-group 0..3
  const int rg = w >> 1;          // row group 0..3
  const int sh = w & 1;           // slot half / col half 0..1
  const int r0b = blockIdx.x * 64;
  const int r0w = r0b + rg * 16;  // this wave's 16 q rows

  const float* qrow = q + (size_t)(r0w + li) * DM + kg * 8;

  floatx4 acc[4];
#pragma unroll
  for (int g = 0; g < 4; ++g) acc[g] = (floatx4){0.f, 0.f, 0.f, 0.f};

  // ======== GEMM1 (exact R8): scores = q @ K^T, f16-split MFMA, 16 chunks ========
#pragma unroll
  for (int p = 0; p < 2; ++p) {
    const _Float16* src = Ks + ((((size_t)0 * 8 + w) * NSLOT + p * 64 + l) << 3);
    load16_lds(src, &r1.stage[0][w][p * 64 + l][0]);
  }
  float4 q0c = *(const float4*)(qrow + 0);
  float4 q1c = *(const float4*)(qrow + 4);
  float4 q0n = *(const float4*)(qrow + 32);
  float4 q1n = *(const float4*)(qrow + 36);
  __syncthreads();

#pragma unroll 2
  for (int c = 0; c < 16; ++c) {
    const int cb = c & 1, nb = cb ^ 1;
    float4 q0nn, q1nn;
    if (c < 15) {
#pragma unroll
      for (int p = 0; p < 2; ++p) {
        const _Float16* src = Ks + ((((size_t)(c + 1) * 8 + w) * NSLOT + p * 64 + l) << 3);
        load16_lds(src, &r1.stage[nb][w][p * 64 + l][0]);
      }
    }
    if (c < 14) {
      q0nn = *(const float4*)(qrow + (c + 2) * 32);
      q1nn = *(const float4*)(qrow + (c + 2) * 32 + 4);
    }
    half8 a1, a2;
#pragma unroll
    for (int j = 0; j < 4; ++j) {
      const float f0 = q0c[j] * 16.0f;   // exact scale
      const float f1 = q1c[j] * 16.0f;
      const _Float16 h0 = (_Float16)f0;
      const _Float16 h1 = (_Float16)f1;
      a1[j]     = h0;  a2[j]     = (_Float16)(f0 - (float)h0);
      a1[4 + j] = h1;  a2[4 + j] = (_Float16)(f1 - (float)h1);
    }
#pragma unroll
    for (int g = 0; g < 4; ++g) {
      const int slot = sh * 64 + g * 16 + li;
      const half8 b1 = *(const half8*)&r1.stage[cb][kg][slot][0];
      const half8 b2 = *(const half8*)&r1.stage[cb][4 + kg][slot][0];
      acc[g] = __builtin_amdgcn_mfma_f32_16x16x32_f16(a1, b1, acc[g], 0, 0, 0);
      acc[g] = __builtin_amdgcn_mfma_f32_16x16x32_f16(a2, b1, acc[g], 0, 0, 0);
      acc[g] = __builtin_amdgcn_mfma_f32_16x16x32_f16(a1, b2, acc[g], 0, 0, 0);
    }
    q0c = q0n; q1c = q1n;
    if (c < 14) { q0n = q0nn; q1n = q1nn; }
    __syncthreads();   // after c==15 stage is dead -> W (union alias) may be zeroed
  }

  // ---- epilogue: scores -> slab; W-zero (region1, stage dead) in the same phase ----
  const float den = sqrtf((float)DM);
#pragma unroll
  for (int g = 0; g < 4; ++g) {
    const int col = sh * 64 + g * 16 + li;
    const float sv = sal[col];
#pragma unroll
    for (int i = 0; i < 4; ++i) {
      const float s = (acc[g][i] * 0.000244140625f) / den + sv;  // *2^-12 exact, IEEE div
      r2.slab[rg * 16 + kg * 4 + i][col] = s;
    }
  }
  {
    uint4* wz = (uint4*)&r1;            // 2*64*136*2 B = 2176 uint4
    const uint4 z4 = {0u, 0u, 0u, 0u};
#pragma unroll
    for (int z = 0; z < 5; ++z) {
      const int idx = t + z * 512;
      if (idx < 2176) wz[idx] = z4;
    }
  }
  __syncthreads();

  // ---- Phase B (exact R8): per-row top-8 (tie: lower index) + softmax. 8 lanes/row. ----
  const int row = t >> 3;   // 0..63
  const int lq  = t & 7;

  float bs[8]; int bi[8];
#pragma unroll
  for (int p = 0; p < 8; ++p) { bs[p] = -3.0e38f; bi[p] = 0x7fffffff; }

#pragma unroll
  for (int jj = 0; jj < 16; ++jj) {
    const int   j = jj * 8 + lq;
    const float s = r2.slab[row][j];
    bool c[8];
#pragma unroll
    for (int p = 0; p < 8; ++p) c[p] = s > bs[p];   // strict > keeps earlier index on ties
    float nb_[8]; int ni[8];
    nb_[0] = c[0] ? s : bs[0];
    ni[0]  = c[0] ? j : bi[0];
#pragma unroll
    for (int p = 7; p >= 1; --p) {
      nb_[p] = c[p] ? (c[p - 1] ? bs[p - 1] : s) : bs[p];
      ni[p]  = c[p] ? (c[p - 1] ? bi[p - 1] : j) : bi[p];
    }
#pragma unroll
    for (int p = 0; p < 8; ++p) { bs[p] = nb_[p]; bi[p] = ni[p]; }
  }

  float ts[8]; int ti_[8];
#pragma unroll
  for (int r = 0; r < 8; ++r) {
    float hs = bs[0]; int hi = bi[0];
#pragma unroll
    for (int m = 1; m <= 4; m <<= 1) {
      const float os = __shfl_xor(hs, m, 64);
      const int   oi = __shfl_xor(hi, m, 64);
      if (os > hs || (os == hs && oi < hi)) { hs = os; hi = oi; }
    }
    ts[r] = hs; ti_[r] = hi;
    if (bs[0] == hs && bi[0] == hi) {
#pragma unroll
      for (int p = 0; p < 7; ++p) { bs[p] = bs[p + 1]; bi[p] = bi[p + 1]; }
      bs[7] = -3.0e38f; bi[7] = 0x7fffffff;
    }
  }

  float tw[8];
  const float mx = ts[0];
  float esum = 0.0f;
#pragma unroll
  for (int r = 0; r < 8; ++r) { tw[r] = expf(ts[r] - mx); esum += tw[r]; }
#pragma unroll
  for (int r = 0; r < 8; ++r) tw[r] /= esum;

  if (lq == 0) {
#pragma unroll
    for (int r = 0; r < 8; ++r) outw[(size_t)(r0b + row) * KSEL + r] = tw[r];
  }

  // ---- scatter this row's 8 weights into W-dense (lane lq writes entry lq; static idx) ----
  {
    float wv = tw[0]; int iv = ti_[0];
#pragma unroll
    for (int r = 1; r < 8; ++r) { if (lq == r) { wv = tw[r]; iv = ti_[r]; } }
    const _Float16 wh = (_Float16)wv;
    const _Float16 wl = (_Float16)(wv - (float)wh);
    r1.W[0][row][iv] = wh;
    r1.W[1][row][iv] = wl;
  }
  __syncthreads();   // slab reads done (region2 reusable) + W complete

  // ======== GEMM2: outv[64 x 512] = W[64 x 128] @ Vt[128 x 512], 8 chunks of 64 cols ======
  // A-fragments (W) are chunk-invariant: hoist to registers (8+8 b128 reads total).
  half8 ah[4], al[4];
#pragma unroll
  for (int ks = 0; ks < 4; ++ks) {
    ah[ks] = *(const half8*)&r1.W[0][rg * 16 + li][ks * 32 + kg * 8];
    al[ks] = *(const half8*)&r1.W[1][rg * 16 + li][ks * 32 + kg * 8];
  }
  // prologue: stage chunk 0 (16KB; wave w covers 2KB)
#pragma unroll
  for (int p = 0; p < 2; ++p) {
    const _Float16* src = Vt + (size_t)0 * 8192 + w * 1024 + p * 512 + l * 8;
    load16_lds(src, &r2.vt[0][w * 1024 + p * 512 + l * 8]);
  }
  __syncthreads();   // drains DMA (and W-frag ds_reads ordered by compiler)

  const int swz = (li & 7) << 4;     // dl&7 == li&7 (sh*32, nt*16 are multiples of 8)
#pragma unroll 2
  for (int cc = 0; cc < 8; ++cc) {
    const int cb = cc & 1, nb = cb ^ 1;
    if (cc < 7) {
#pragma unroll
      for (int p = 0; p < 2; ++p) {
        const _Float16* src = Vt + (size_t)(cc + 1) * 8192 + w * 1024 + p * 512 + l * 8;
        load16_lds(src, &r2.vt[nb][w * 1024 + p * 512 + l * 8]);
      }
    }
    floatx4 acc2[2];
#pragma unroll
    for (int nt = 0; nt < 2; ++nt) acc2[nt] = (floatx4){0.f, 0.f, 0.f, 0.f};
#pragma unroll
    for (int ks = 0; ks < 4; ++ks) {
#pragma unroll
      for (int nt = 0; nt < 2; ++nt) {
        const int dl  = sh * 32 + nt * 16 + li;                 // d-col within chunk
        const int ofs = (dl * 256 + ks * 64 + kg * 16) ^ swz;   // swizzled byte offset
        const half8 bv = *(const half8*)((const char*)&r2.vt[cb][0] + ofs);
        acc2[nt] = __builtin_amdgcn_mfma_f32_16x16x32_f16(ah[ks], bv, acc2[nt], 0, 0, 0);
        acc2[nt] = __builtin_amdgcn_mfma_f32_16x16x32_f16(al[ks], bv, acc2[nt], 0, 0, 0);
      }
    }
    // D-frag: col = li (d), row = kg*4 + i (within rg's 16 rows)
#pragma unroll
    for (int nt = 0; nt < 2; ++nt)
#pragma unroll
      for (int i = 0; i < 4; ++i)
        outv[(size_t)(r0b + rg * 16 + kg * 4 + i) * DM + cc * 64 + sh * 32 + nt * 16 + li]
            = acc2[nt][i];
    __syncthreads();   // all waves done reading vt[cb]; next iter's stage targets it
  }
}

extern "C" void kernel_launch(void* const* d_in, const int* in_sizes, int n_in,
                              void* d_out, int out_size, void* d_ws, size_t ws_size,
                              hipStream_t stream) {
  const float* q   = (const float*)d_in[0];
  const float* Km  = (const float*)d_in[1];
  const float* Vm  = (const float*)d_in[2];
  const float* sal = (const float*)d_in[3];
  // d_in[4] = topk (fixed 8)

  float* outv = (float*)d_out;
  float* outw = outv + (size_t)R_TOTAL * DM;

  _Float16* Ks = (_Float16*)d_ws;                    // 256 KB
  _Float16* Vt = Ks + (size_t)16 * 8 * NSLOT * 8;    // 128 KB

  hipLaunchKernelGGL(smb_prep, dim3((NSLOT * DM) / 256), dim3(256), 0, stream, Km, Vm, Ks, Vt);
  hipLaunchKernelGGL(smb_main, dim3(R_TOTAL / 64), dim3(512), 0, stream,
                     q, Ks, Vt, sal, outv, outw);
}